// Round 1
// baseline (395.462 us; speedup 1.0000x reference)
//
#include <hip/hip_runtime.h>

// CoordinateDescent: B=8, M=N=2048, R=32, f32 in/out.
// l1_u = l2_u = l1_v = l2_v = 0.01*0.5*2048 = 10.24
#define NB 8
#define MD 2048
#define ND 2048
#define RD 32
#define KC 32
#define MT 128
#define KSPLIT 4

// b[b,i,j] = sum_n w[b,n,i] * w[b,n,j]   (w: [B,2048,32])
// grid: NB*RD blocks x 256 threads; block -> (batch, i); thread -> (slice, j)
__global__ __launch_bounds__(256) void bmat_kernel(const float* __restrict__ w,
                                                   float* __restrict__ bmat) {
    int blk = blockIdx.x;
    int batch = blk >> 5;
    int i = blk & 31;
    int t = threadIdx.x;
    int j = t & 31;
    int slice = t >> 5;  // 0..7
    const float* wb = w + (size_t)batch * ND * RD;
    float acc = 0.f;
    int n0 = slice * (ND / 8);
    for (int n = n0; n < n0 + ND / 8; ++n) {
        acc = fmaf(wb[n * RD + i], wb[n * RD + j], acc);
    }
    __shared__ float red[8][32];
    red[slice][j] = acc;
    __syncthreads();
    if (t < 32) {
        float s = 0.f;
#pragma unroll
        for (int q = 0; q < 8; ++q) s += red[q][j];
        bmat[((size_t)batch * RD + i) * RD + j] = s;
    }
}

// a[b,row,r] += sum_k xAcc(b,row,k) * w[b,k,r]
//   TRANS=false: xAcc = x[b,row,k]   (a1 = x @ v)
//   TRANS=true : xAcc = x[b,k,row]   (a2 = x^T @ u_new)
// block=128 threads, out tile MT=128 rows x 32 cols, thread tile 4x8,
// split-K x4 with atomicAdd epilogue (a must be zeroed first).
template <bool TRANS>
__global__ __launch_bounds__(128) void gemm_kernel(const float* __restrict__ x,
                                                   const float* __restrict__ w,
                                                   float* __restrict__ a) {
    __shared__ float xsT[KC][MT + 4];  // [k][row], padded
    __shared__ float wsm[KC][RD];      // [k][r]
    int bz = blockIdx.x;
    int ks = bz & (KSPLIT - 1);
    int tile = (bz >> 2) & 15;
    int batch = bz >> 6;
    int m0 = tile * MT;
    int t = threadIdx.x;
    int rowgrp = t & 31;
    int colgrp = t >> 5;
    int r4 = rowgrp * 4;
    int c8 = colgrp * 8;
    float acc[4][8];
#pragma unroll
    for (int i = 0; i < 4; ++i)
#pragma unroll
        for (int j = 0; j < 8; ++j) acc[i][j] = 0.f;

    const size_t xbase = (size_t)batch * MD * ND;
    const float* wb = w + (size_t)batch * 2048 * RD;

    for (int c = 0; c < (2048 / KSPLIT) / KC; ++c) {
        int k0 = ks * (2048 / KSPLIT) + c * KC;
        if (!TRANS) {
            // load x[b, m0+row, k0..k0+31], store transposed -> xsT[k][row]
#pragma unroll
            for (int i = 0; i < 8; ++i) {
                int idx = t + i * 128;
                int row = idx >> 3;
                int kq = (idx & 7) * 4;
                float4 xv = *(const float4*)(x + xbase + (size_t)(m0 + row) * ND + k0 + kq);
                xsT[kq + 0][row] = xv.x;
                xsT[kq + 1][row] = xv.y;
                xsT[kq + 2][row] = xv.z;
                xsT[kq + 3][row] = xv.w;
            }
        } else {
            // load x[b, k0+kk, m0..m0+127] -> xsT[kk][row] directly (coalesced)
#pragma unroll
            for (int i = 0; i < 8; ++i) {
                int idx = t + i * 128;
                int kk = idx >> 5;
                int c4 = (idx & 31) * 4;
                float4 xv = *(const float4*)(x + xbase + (size_t)(k0 + kk) * ND + m0 + c4);
                *(float4*)&xsT[kk][c4] = xv;
            }
        }
#pragma unroll
        for (int i = 0; i < 2; ++i) {
            int idx = t + i * 128;
            int kk = idx >> 3;
            int rq = (idx & 7) * 4;
            *(float4*)&wsm[kk][rq] = *(const float4*)(wb + (size_t)(k0 + kk) * RD + rq);
        }
        __syncthreads();
#pragma unroll 4
        for (int kk = 0; kk < KC; ++kk) {
            float4 xr = *(float4*)&xsT[kk][r4];
            float4 w0 = *(float4*)&wsm[kk][c8];
            float4 w1 = *(float4*)&wsm[kk][c8 + 4];
            float xv[4] = {xr.x, xr.y, xr.z, xr.w};
            float wv[8] = {w0.x, w0.y, w0.z, w0.w, w1.x, w1.y, w1.z, w1.w};
#pragma unroll
            for (int i = 0; i < 4; ++i)
#pragma unroll
                for (int j = 0; j < 8; ++j) acc[i][j] = fmaf(xv[i], wv[j], acc[i][j]);
        }
        __syncthreads();
    }
    float* ab = a + ((size_t)batch * 2048 + m0) * RD;
#pragma unroll
    for (int i = 0; i < 4; ++i)
#pragma unroll
        for (int j = 0; j < 8; ++j)
            atomicAdd(ab + (size_t)(r4 + i) * RD + c8 + j, acc[i][j]);
}

// Gauss-Seidel over r=0..31, fully parallel over (batch, row).
// One thread per row; u_row and a_row live in registers; b in LDS.
// b is symmetric (bitwise, by construction) -> read rows of b, vectorized.
__global__ __launch_bounds__(256) void gs_kernel(const float* __restrict__ uin,
                                                 const float* __restrict__ amat,
                                                 const float* __restrict__ bmat,
                                                 float* __restrict__ uout,
                                                 float l1, float l2) {
    int blk = blockIdx.x;
    int batch = blk >> 3;
    int m = (blk & 7) * 256 + threadIdx.x;
    __shared__ float bs[RD][RD];
    ((float4*)&bs[0][0])[threadIdx.x] =
        ((const float4*)(bmat + (size_t)batch * RD * RD))[threadIdx.x];
    __syncthreads();
    float u[RD], av[RD];
    const float* up = uin + ((size_t)batch * 2048 + m) * RD;
    const float* ap = amat + ((size_t)batch * 2048 + m) * RD;
#pragma unroll
    for (int q = 0; q < 8; ++q) {
        *(float4*)&u[q * 4] = *(const float4*)&up[q * 4];
        *(float4*)&av[q * 4] = *(const float4*)&ap[q * 4];
    }
#pragma unroll
    for (int r = 0; r < RD; ++r) {
        float brr = bs[r][r];
        float t2 = -u[r] * brr;
#pragma unroll
        for (int k = 0; k < RD; ++k) t2 = fmaf(u[k], bs[r][k], t2);
        float num = av[r] - t2;
        float mag = fmaxf(fabsf(num) - l1, 0.f);
        num = copysignf(mag, num);
        u[r] = (num + 1e-16f) / (brr + l2 + 1e-16f);
    }
    float* op = uout + ((size_t)batch * 2048 + m) * RD;
#pragma unroll
    for (int q = 0; q < 8; ++q) *(float4*)&op[q * 4] = *(float4*)&u[q * 4];
}

extern "C" void kernel_launch(void* const* d_in, const int* in_sizes, int n_in,
                              void* d_out, int out_size, void* d_ws, size_t ws_size,
                              hipStream_t stream) {
    const float* x = (const float*)d_in[0];
    const float* u = (const float*)d_in[1];
    const float* v = (const float*)d_in[2];
    float* out_u = (float*)d_out;
    float* out_v = out_u + (size_t)NB * MD * RD;
    float* a_ws = (float*)d_ws;                       // [B,2048,32] f32 = 2 MB
    float* b_ws = a_ws + (size_t)NB * 2048 * RD;      // [B,32,32]   f32 = 32 KB
    const float l1u = 10.24f, l2u = 10.24f;           // 0.01*0.5*2048
    const float l1v = 10.24f, l2v = 10.24f;           // 0.01*0.5*2048
    size_t abytes = (size_t)NB * 2048 * RD * sizeof(float);

    // ---- factor 0: update u ----
    bmat_kernel<<<NB * RD, 256, 0, stream>>>(v, b_ws);
    hipMemsetAsync(a_ws, 0, abytes, stream);
    gemm_kernel<false><<<NB * 16 * KSPLIT, 128, 0, stream>>>(x, v, a_ws);
    gs_kernel<<<NB * 8, 256, 0, stream>>>(u, a_ws, b_ws, out_u, l1u, l2u);

    // ---- factor 1: update v (x transposed, w = u_new) ----
    bmat_kernel<<<NB * RD, 256, 0, stream>>>(out_u, b_ws);
    hipMemsetAsync(a_ws, 0, abytes, stream);
    gemm_kernel<true><<<NB * 16 * KSPLIT, 128, 0, stream>>>(x, out_u, a_ws);
    gs_kernel<<<NB * 8, 256, 0, stream>>>(v, a_ws, b_ws, out_v, l1v, l2v);
}

// Round 2
// 257.426 us; speedup vs baseline: 1.5362x; 1.5362x over previous
//
#include <hip/hip_runtime.h>
#include <hip/hip_bf16.h>

// CoordinateDescent: B=8, M=N=2048, R=32, f32 in/out.
// l1 = l2 = 0.01*0.5*2048 = 10.24 for both factors.
#define NB 8
#define MD 2048
#define RD 32
#define KSPLIT 4
#define KSL (2048 / KSPLIT)  // 512
#define VT_STRIDE 520        // shorts per row of wT (512 + 8 pad), 1040B = 16B-aligned
#define XT_STRIDE 40         // shorts per row of xT (32 + 8 pad), 80B = 16B-aligned

typedef float floatx4 __attribute__((ext_vector_type(4)));
typedef short shortx8 __attribute__((ext_vector_type(8)));

static __device__ __forceinline__ short f2b(float f) {
    __hip_bfloat16 h = __float2bfloat16(f);
    return (short)*reinterpret_cast<unsigned short*>(&h);
}

// -------- b[b,i,j] = sum_n w[b,n,i]*w[b,n,j], atomic partial per 64-row slice --------
// grid: NB*32 blocks x 256 thr. Requires bmat zeroed beforehand.
__global__ __launch_bounds__(256) void bmat_kernel(const float* __restrict__ w,
                                                   float* __restrict__ bmat) {
    int batch = blockIdx.x >> 5;
    int n0 = (blockIdx.x & 31) * 64;
    int t = threadIdx.x;
    __shared__ float ws[64][36];  // row stride 144B: 16B-aligned for float4 reads
    const float* wb = w + ((size_t)batch * 2048 + n0) * RD;
#pragma unroll
    for (int i = 0; i < 8; ++i) {
        int idx = t + i * 256;
        ws[idx >> 5][idx & 31] = wb[(idx >> 5) * RD + (idx & 31)];
    }
    __syncthreads();
    int ii = t >> 3;
    int jq = (t & 7) * 4;
    float acc[4] = {0.f, 0.f, 0.f, 0.f};
    for (int n = 0; n < 64; ++n) {
        float wi = ws[n][ii];
        float4 wj = *(const float4*)&ws[n][jq];
        acc[0] = fmaf(wi, wj.x, acc[0]);
        acc[1] = fmaf(wi, wj.y, acc[1]);
        acc[2] = fmaf(wi, wj.z, acc[2]);
        acc[3] = fmaf(wi, wj.w, acc[3]);
    }
    float* bp = bmat + ((size_t)batch * RD + ii) * RD + jq;
#pragma unroll
    for (int c = 0; c < 4; ++c) atomicAdd(bp + c, acc[c]);
}

// -------- GEMM1: a[b,m,r] += sum_k x[b,m,k] * v[b,k,r]  (bf16 MFMA, split-K) --------
// grid: NB*32*KSPLIT = 1024 blocks x 256 thr (4 waves, 16 rows each).
__global__ __launch_bounds__(256, 4) void gemm1_kernel(const float* __restrict__ x,
                                                       const float* __restrict__ v,
                                                       float* __restrict__ a) {
    __shared__ short wT[32 * VT_STRIDE];  // vT[r][k] bf16, k slice-local
    int bz = blockIdx.x;
    int ks = bz & (KSPLIT - 1);
    int mblk = (bz >> 2) & 31;
    int batch = bz >> 7;
    int t = threadIdx.x;
    int lane = t & 63;
    int wave = t >> 6;

    // stage vT: v[ks*KSL + k][r] -> wT[r][k], one-time, coalesced f32 loads
    const float* wb = v + ((size_t)batch * 2048 + ks * KSL) * RD;
#pragma unroll
    for (int i = 0; i < 16; ++i) {
        int idx = t + i * 256;
        int k = idx >> 3;
        int rq = (idx & 7) * 4;
        float4 f = *(const float4*)(wb + (size_t)k * RD + rq);
        wT[(rq + 0) * VT_STRIDE + k] = f2b(f.x);
        wT[(rq + 1) * VT_STRIDE + k] = f2b(f.y);
        wT[(rq + 2) * VT_STRIDE + k] = f2b(f.z);
        wT[(rq + 3) * VT_STRIDE + k] = f2b(f.w);
    }
    __syncthreads();

    // A-frag: A[m=lane&15][k=(lane>>4)*8+j], direct from global x (f32 -> bf16)
    int kq = (lane >> 4) * 8;
    const float* xrow =
        x + ((size_t)batch * MD + mblk * 64 + wave * 16 + (lane & 15)) * 2048 + ks * KSL + kq;
    int r0 = (lane & 15) * VT_STRIDE + kq;
    int r1 = ((lane & 15) + 16) * VT_STRIDE + kq;

    floatx4 acc0 = {0.f, 0.f, 0.f, 0.f}, acc1 = {0.f, 0.f, 0.f, 0.f};
    float4 fa = *(const float4*)(xrow);
    float4 fb = *(const float4*)(xrow + 4);
    for (int s = 0; s < KSL / 32; ++s) {
        float4 na = {0, 0, 0, 0}, nb = {0, 0, 0, 0};
        if (s + 1 < KSL / 32) {  // register prefetch of next A-tile
            na = *(const float4*)(xrow + (s + 1) * 32);
            nb = *(const float4*)(xrow + (s + 1) * 32 + 4);
        }
        shortx8 af = {f2b(fa.x), f2b(fa.y), f2b(fa.z), f2b(fa.w),
                      f2b(fb.x), f2b(fb.y), f2b(fb.z), f2b(fb.w)};
        shortx8 b0 = *(const shortx8*)&wT[r0 + s * 32];
        shortx8 b1 = *(const shortx8*)&wT[r1 + s * 32];
        acc0 = __builtin_amdgcn_mfma_f32_16x16x32_bf16(af, b0, acc0, 0, 0, 0);
        acc1 = __builtin_amdgcn_mfma_f32_16x16x32_bf16(af, b1, acc1, 0, 0, 0);
        fa = na;
        fb = nb;
    }
    // D: col = lane&15, row = (lane>>4)*4 + i
    float* ab = a + ((size_t)batch * 2048 + mblk * 64 + wave * 16 + (lane >> 4) * 4) * RD + (lane & 15);
#pragma unroll
    for (int i = 0; i < 4; ++i) {
        atomicAdd(ab + i * RD, acc0[i]);
        atomicAdd(ab + i * RD + 16, acc1[i]);
    }
}

// -------- GEMM2: a[b,n,r] += sum_m x[b,m,n] * u[b,m,r]  (bf16 MFMA, split-K over m) ----
// Per-step wave-private LDS transpose of the 32x16 x-tile; no per-step barriers.
__global__ __launch_bounds__(256, 4) void gemm2_kernel(const float* __restrict__ x,
                                                       const float* __restrict__ u,
                                                       float* __restrict__ a) {
    __shared__ short uT[32 * VT_STRIDE];       // uT[r][m] bf16
    __shared__ short xT[4 * 16 * XT_STRIDE];   // per-wave 16n x 32m bf16
    int bz = blockIdx.x;
    int ks = bz & (KSPLIT - 1);
    int nblk = (bz >> 2) & 31;
    int batch = bz >> 7;
    int t = threadIdx.x;
    int lane = t & 63;
    int wave = t >> 6;

    const float* ub = u + ((size_t)batch * 2048 + ks * KSL) * RD;
#pragma unroll
    for (int i = 0; i < 16; ++i) {
        int idx = t + i * 256;
        int k = idx >> 3;
        int rq = (idx & 7) * 4;
        float4 f = *(const float4*)(ub + (size_t)k * RD + rq);
        uT[(rq + 0) * VT_STRIDE + k] = f2b(f.x);
        uT[(rq + 1) * VT_STRIDE + k] = f2b(f.y);
        uT[(rq + 2) * VT_STRIDE + k] = f2b(f.z);
        uT[(rq + 3) * VT_STRIDE + k] = f2b(f.w);
    }
    __syncthreads();

    short* xTw = &xT[wave * 16 * XT_STRIDE];
    int mloc = lane & 31;            // row of the 32-row k-step tile this lane loads
    int ng = (lane >> 5) * 8;        // wave-local col group (0 or 8)
    int n0w = nblk * 64 + wave * 16;
    const float* xp = x + ((size_t)batch * 2048 + ks * KSL + mloc) * 2048 + n0w + ng;

    int nl = lane & 15;
    int kq = (lane >> 4) * 8;
    int rA = nl * XT_STRIDE + kq;
    int rB0 = nl * VT_STRIDE + kq;
    int rB1 = (nl + 16) * VT_STRIDE + kq;

    floatx4 acc0 = {0.f, 0.f, 0.f, 0.f}, acc1 = {0.f, 0.f, 0.f, 0.f};
    float4 fa = *(const float4*)xp;
    float4 fb = *(const float4*)(xp + 4);
    for (int s = 0; s < KSL / 32; ++s) {
        // transpose-store this step's x tile (wave-private; in-order DS = safe)
        xTw[(ng + 0) * XT_STRIDE + mloc] = f2b(fa.x);
        xTw[(ng + 1) * XT_STRIDE + mloc] = f2b(fa.y);
        xTw[(ng + 2) * XT_STRIDE + mloc] = f2b(fa.z);
        xTw[(ng + 3) * XT_STRIDE + mloc] = f2b(fa.w);
        xTw[(ng + 4) * XT_STRIDE + mloc] = f2b(fb.x);
        xTw[(ng + 5) * XT_STRIDE + mloc] = f2b(fb.y);
        xTw[(ng + 6) * XT_STRIDE + mloc] = f2b(fb.z);
        xTw[(ng + 7) * XT_STRIDE + mloc] = f2b(fb.w);
        float4 na = {0, 0, 0, 0}, nb = {0, 0, 0, 0};
        if (s + 1 < KSL / 32) {  // prefetch next 32 rows
            na = *(const float4*)(xp + (size_t)(s + 1) * 32 * 2048);
            nb = *(const float4*)(xp + (size_t)(s + 1) * 32 * 2048 + 4);
        }
        shortx8 af = *(const shortx8*)&xTw[rA];
        shortx8 b0 = *(const shortx8*)&uT[rB0 + s * 32];
        shortx8 b1 = *(const shortx8*)&uT[rB1 + s * 32];
        acc0 = __builtin_amdgcn_mfma_f32_16x16x32_bf16(af, b0, acc0, 0, 0, 0);
        acc1 = __builtin_amdgcn_mfma_f32_16x16x32_bf16(af, b1, acc1, 0, 0, 0);
        fa = na;
        fb = nb;
    }
    float* ab = a + ((size_t)batch * 2048 + n0w + (lane >> 4) * 4) * RD + (lane & 15);
#pragma unroll
    for (int i = 0; i < 4; ++i) {
        atomicAdd(ab + i * RD, acc0[i]);
        atomicAdd(ab + i * RD + 16, acc1[i]);
    }
}

// -------- Gauss-Seidel over r, parallel over (batch,row) --------
__global__ __launch_bounds__(256) void gs_kernel(const float* __restrict__ uin,
                                                 const float* __restrict__ amat,
                                                 const float* __restrict__ bmat,
                                                 float* __restrict__ uout,
                                                 float l1, float l2) {
    int blk = blockIdx.x;
    int batch = blk >> 3;
    int m = (blk & 7) * 256 + threadIdx.x;
    __shared__ float bs[RD][RD];
    ((float4*)&bs[0][0])[threadIdx.x] =
        ((const float4*)(bmat + (size_t)batch * RD * RD))[threadIdx.x];
    __syncthreads();
    float uv[RD], av[RD];
    const float* up = uin + ((size_t)batch * 2048 + m) * RD;
    const float* ap = amat + ((size_t)batch * 2048 + m) * RD;
#pragma unroll
    for (int q = 0; q < 8; ++q) {
        *(float4*)&uv[q * 4] = *(const float4*)&up[q * 4];
        *(float4*)&av[q * 4] = *(const float4*)&ap[q * 4];
    }
#pragma unroll
    for (int r = 0; r < RD; ++r) {
        float brr = bs[r][r];
        float t2 = -uv[r] * brr;
#pragma unroll
        for (int k = 0; k < RD; ++k) t2 = fmaf(uv[k], bs[r][k], t2);
        float num = av[r] - t2;
        float mag = fmaxf(fabsf(num) - l1, 0.f);
        num = copysignf(mag, num);
        uv[r] = (num + 1e-16f) / (brr + l2 + 1e-16f);
    }
    float* op = uout + ((size_t)batch * 2048 + m) * RD;
#pragma unroll
    for (int q = 0; q < 8; ++q) *(float4*)&op[q * 4] = *(float4*)&uv[q * 4];
}

extern "C" void kernel_launch(void* const* d_in, const int* in_sizes, int n_in,
                              void* d_out, int out_size, void* d_ws, size_t ws_size,
                              hipStream_t stream) {
    const float* x = (const float*)d_in[0];
    const float* u = (const float*)d_in[1];
    const float* v = (const float*)d_in[2];
    float* out_u = (float*)d_out;
    float* out_v = out_u + (size_t)NB * MD * RD;
    float* a_ws = (float*)d_ws;                    // [B,2048,32] f32 = 2 MB
    float* b_ws = a_ws + (size_t)NB * 2048 * RD;   // [B,32,32]   f32 = 32 KB (adjacent)
    const float l1u = 10.24f, l2u = 10.24f;
    const float l1v = 10.24f, l2v = 10.24f;
    size_t abytes = (size_t)NB * 2048 * RD * sizeof(float);
    size_t bbytes = (size_t)NB * RD * RD * sizeof(float);

    // ---- factor 0: update u ----
    hipMemsetAsync(a_ws, 0, abytes + bbytes, stream);
    bmat_kernel<<<NB * 32, 256, 0, stream>>>(v, b_ws);
    gemm1_kernel<<<NB * 32 * KSPLIT, 256, 0, stream>>>(x, v, a_ws);
    gs_kernel<<<NB * 8, 256, 0, stream>>>(u, a_ws, b_ws, out_u, l1u, l2u);

    // ---- factor 1: update v ----
    hipMemsetAsync(a_ws, 0, abytes + bbytes, stream);
    bmat_kernel<<<NB * 32, 256, 0, stream>>>(out_u, b_ws);
    gemm2_kernel<<<NB * 32 * KSPLIT, 256, 0, stream>>>(x, out_u, a_ws);
    gs_kernel<<<NB * 8, 256, 0, stream>>>(v, a_ws, b_ws, out_v, l1v, l2v);
}